// Round 6
// baseline (332.746 us; speedup 1.0000x reference)
//
#include <hip/hip_runtime.h>
#include <hip/hip_cooperative_groups.h>

namespace cg = cooperative_groups;

// Problem constants
#define LSEQ 1024
#define DMODEL 1024
#define NHEADS 16
#define FDIM 16
#define HDIM 64
#define CHUNK 64
#define NCHUNK 16
#define NSPLIT 4

typedef __attribute__((ext_vector_type(8))) short short8;   // 8 bf16 (4 VGPRs)
typedef __attribute__((ext_vector_type(4))) float floatx4;  // MFMA acc

// Hardware RNE f32->bf16 (v_cvt_pk_bf16_f32).
__device__ __forceinline__ unsigned short f2bf(float f) {
    return __builtin_bit_cast(unsigned short, (__bf16)f);
}

// Workspace layout (ushort indices):
//   qbB @0        (262144)   bf16 q   [1024][256]   row-major [l][h*16+d]
//   kbB @262144   (262144)   bf16 k   [1024][256]   row-major
//   vtB @524288   (1048576)  bf16 v^T [1024][1024]  TRANSPOSED: [h*64+d][l]
//   ybB @1572864  (1048576)  bf16 y   [1024][1024]
//   fp32 partials @ byte offset 5242880:
//   numW  [256][4][64][64] fp32   (4194304 floats)   [c*16+h][s][qrow][d]
//   denW  [256][4][64]     fp32   (65536 floats)
#define U_QB   0
#define U_KB   262144
#define U_VT   524288
#define U_YB   1572864
#define U_END  2621440

#define MFMA(a, b, c) __builtin_amdgcn_mfma_f32_16x16x32_bf16((a), (b), (c), 0, 0, 0)

// Per-block dtype detector: samples 1024 ushorts of Wq. bf16 data -> exponents
// cluster tightly (bad ~0%); fp32-as-ushort -> ~30%+ "bad". Returns 1 if fp32.
// Runs uniformly in every block (contains __syncthreads).
__device__ __forceinline__ int block_detect_fp32(const unsigned short* wq, int* cnt) {
    if (threadIdx.x == 0) *cnt = 0;
    __syncthreads();
    int bad = 0;
    for (int i = threadIdx.x; i < 1024; i += blockDim.x) {
        int e = (wq[i] >> 7) & 0xFF;
        if (e >= 143 || (e > 0 && e <= 80)) bad++;
    }
    if (bad) atomicAdd(cnt, bad);
    __syncthreads();
    return *cnt > 128;
}

// ---------------------------------------------------------------------------
// Pipelined 64x64 GEMM tile body over K = [kbeg, kend), BK = 128:
// C(64x64) += A[arow0:+64] @ B[brow0:+64]^T, lda = ldb = 1024.
// t = 0..255. Iter k+1's global loads issue right after the LDS-ready
// barrier, overlapping the 16 MFMAs. fp32 inputs staged with float4 loads +
// HW cvt. acc order: 00,01,10,11 (mi*2+ni).
// ---------------------------------------------------------------------------
__device__ __forceinline__ void gemm64_body(
    int t, unsigned short (*As)[136], unsigned short (*Bs)[136],
    const void* Araw, int a_fp32, int arow0,
    const void* Braw, int b_fp32, int brow0,
    int kbeg, int kend, floatx4 acc[4]) {
    int r = t >> 2, c0 = (t & 3) * 32;
    int wave = (t >> 6) & 3, lane = t & 63;
    int ml = lane & 15, q4 = lane >> 4;
    int mq = (wave >> 1) * 32, nq = (wave & 1) * 32;
    #pragma unroll
    for (int i = 0; i < 4; ++i) acc[i] = (floatx4){0.f, 0.f, 0.f, 0.f};

    short8 av[4], bv[4], av2[4], bv2[4];
    auto cvt8 = [](float4 f0, float4 f1) {
        short8 x;
        x[0] = (short)f2bf(f0.x); x[1] = (short)f2bf(f0.y);
        x[2] = (short)f2bf(f0.z); x[3] = (short)f2bf(f0.w);
        x[4] = (short)f2bf(f1.x); x[5] = (short)f2bf(f1.y);
        x[6] = (short)f2bf(f1.z); x[7] = (short)f2bf(f1.w);
        return x;
    };
    auto stage = [&](int k0, short8* a, short8* b) {
        if (!a_fp32) {
            const unsigned short* Ap = (const unsigned short*)Araw + (size_t)(arow0 + r) * DMODEL + k0 + c0;
            #pragma unroll
            for (int j = 0; j < 4; ++j) a[j] = *(const short8*)(Ap + j * 8);
        } else {
            const float* Ap = (const float*)Araw + (size_t)(arow0 + r) * DMODEL + k0 + c0;
            #pragma unroll
            for (int j = 0; j < 4; ++j)
                a[j] = cvt8(*(const float4*)(Ap + j * 8), *(const float4*)(Ap + j * 8 + 4));
        }
        if (!b_fp32) {
            const unsigned short* Bp = (const unsigned short*)Braw + (size_t)(brow0 + r) * DMODEL + k0 + c0;
            #pragma unroll
            for (int j = 0; j < 4; ++j) b[j] = *(const short8*)(Bp + j * 8);
        } else {
            const float* Bp = (const float*)Braw + (size_t)(brow0 + r) * DMODEL + k0 + c0;
            #pragma unroll
            for (int j = 0; j < 4; ++j)
                b[j] = cvt8(*(const float4*)(Bp + j * 8), *(const float4*)(Bp + j * 8 + 4));
        }
    };

    stage(kbeg, av, bv);
    for (int k0 = kbeg; k0 < kend; k0 += 128) {
        __syncthreads();   // previous iter's LDS reads done
        #pragma unroll
        for (int j = 0; j < 4; ++j) {
            *(short8*)&As[r][c0 + j * 8] = av[j];
            *(short8*)&Bs[r][c0 + j * 8] = bv[j];
        }
        __syncthreads();   // LDS ready
        if (k0 + 128 < kend) stage(k0 + 128, av2, bv2);   // overlap with MFMA
        #pragma unroll
        for (int kk = 0; kk < 4; ++kk) {
            short8 a0 = *(const short8*)&As[mq + ml][kk * 32 + q4 * 8];
            short8 a1 = *(const short8*)&As[mq + 16 + ml][kk * 32 + q4 * 8];
            short8 b0 = *(const short8*)&Bs[nq + ml][kk * 32 + q4 * 8];
            short8 b1 = *(const short8*)&Bs[nq + 16 + ml][kk * 32 + q4 * 8];
            acc[0] = MFMA(a0, b0, acc[0]); acc[1] = MFMA(a0, b1, acc[1]);
            acc[2] = MFMA(a1, b0, acc[2]); acc[3] = MFMA(a1, b1, acc[3]);
        }
        #pragma unroll
        for (int j = 0; j < 4; ++j) { av[j] = av2[j]; bv[j] = bv2[j]; }
    }
}

// ---------------------------------------------------------------------------
// Flash unit: one (h, c, s) kv-range quarter. S = 1 + qk/4 + (qk)^2/32,
// causal; writes fp32 partial num/den for split s. No early returns (safe
// inside a cooperative kernel). QK^T swapped (MFMA(K,Q)) -> vectorized P
// store; PV transposed (MFMA(vT,P)) -> float4 partial stores, shuffle-free
// den. LDS arrays passed in (union buffer).
// ---------------------------------------------------------------------------
__device__ __forceinline__ void flash_unit(
    int u,
    unsigned short (*qs)[40], unsigned short (*ksm)[40],
    unsigned short (*vT)[72], unsigned short (*P)[72],
    const unsigned short* __restrict__ qb, const unsigned short* __restrict__ kb,
    const unsigned short* __restrict__ vt,
    float* __restrict__ numW, float* __restrict__ denW) {
    int idx = u & 255;                   // (h, c)
    int s = u >> 8;                      // kv-range quarter, 0..3
    int h = idx & 15, c = idx >> 4;
    int n = c + 1;
    int j0 = (n * s) >> 2;
    int j1 = ((n * (s + 1)) >> 2) - 1;   // inclusive; empty when j0 > j1
    int l0 = c * CHUNK;
    int t = threadIdx.x, lane = t & 63, wave = t >> 6;
    int ml = lane & 15, q4 = lane >> 4;
    int m0 = wave * 16;
    int sm = t >> 2, si4 = (t & 3) * 4, sc16 = (t & 3) * 16;

    // ---- staging: q rows (zero-padded K=32), vT pad rows
    {
        *(ushort4*)&qs[sm][si4] = *(const ushort4*)&qb[(size_t)(l0 + sm) * 256 + h * 16 + si4];
        ushort4 z = {0, 0, 0, 0};
        *(ushort4*)&qs[sm][16 + si4]  = z;
        *(ushort4*)&ksm[sm][16 + si4] = z;   // k pad, persists across tiles
    }
    if (t < 64) {
        vT[64][t] = 0x3F80;   // 1.0 bf16 (denominator row)
        #pragma unroll
        for (int i = 65; i < 80; ++i) vT[i][t] = 0;
    }

    auto load_kv = [&](int j, ushort4& kr, short8& v0, short8& v1) {
        kr = *(const ushort4*)&kb[(size_t)(j * 64 + sm) * 256 + h * 16 + si4];
        const unsigned short* vp = vt + (size_t)(h * 64 + sm) * 1024 + j * 64 + sc16;
        v0 = *(const short8*)vp;
        v1 = *(const short8*)(vp + 8);
    };

    floatx4 acc[5];
    #pragma unroll
    for (int i = 0; i < 5; ++i) acc[i] = (floatx4){0.f, 0.f, 0.f, 0.f};

    ushort4 kr, kr2; short8 va, vb2, va2, vb22;
    if (j0 <= j1) {
        load_kv(j0, kr, va, vb2);
        for (int j = j0; j <= j1; ++j) {
            // ---- write prefetched k_j / v_j^T to LDS (all vectorized)
            *(ushort4*)&ksm[sm][si4] = kr;
            *(short8*)&vT[sm][sc16]     = va;
            *(short8*)&vT[sm][sc16 + 8] = vb2;
            __syncthreads();   // staging visible (also covers qs/pads on first iter)
            if (j < j1) load_kv(j + 1, kr2, va2, vb22);   // overlap with MFMAs

            // ---- scores, swapped: MFMA(K,Q) -> lane(q4,ml) reg r holds
            // S[q=m0+ml][t=nt*16+q4*4+r]; P row store is one ushort4 per nt.
            short8 aq = *(const short8*)&qs[m0 + ml][q4 * 8];
            bool diag = (j == c);
            int qloc = m0 + ml;
            #pragma unroll
            for (int nt = 0; nt < 4; ++nt) {
                short8 bk = *(const short8*)&ksm[nt * 16 + ml][q4 * 8];
                floatx4 s4 = {0.f, 0.f, 0.f, 0.f};
                s4 = MFMA(bk, aq, s4);
                ushort4 pw;
                #pragma unroll
                for (int r = 0; r < 4; ++r) {
                    int tloc = nt * 16 + q4 * 4 + r;
                    float sc = s4[r];
                    float p = 1.f + 0.25f * sc + 0.03125f * sc * sc;
                    if (diag && tloc > qloc) p = 0.f;
                    ((unsigned short*)&pw)[r] = f2bf(p);
                }
                *(ushort4*)&P[qloc][nt * 16 + q4 * 4] = pw;
            }
            // P rows are wave-private: no barrier needed before PV.

            // ---- PV transposed: acc[nt] = O^T block (A = vT rows, B = P rows)
            #pragma unroll
            for (int k0 = 0; k0 < 64; k0 += 32) {
                short8 ap = *(const short8*)&P[m0 + ml][k0 + q4 * 8];
                #pragma unroll
                for (int nt = 0; nt < 5; ++nt) {
                    short8 av = *(const short8*)&vT[nt * 16 + ml][k0 + q4 * 8];
                    acc[nt] = MFMA(av, ap, acc[nt]);
                }
            }
            __syncthreads();   // protect ksm/vT from next tile's staging
            kr = kr2; va = va2; vb2 = vb22;
        }
    }

    // ---- write fp32 partials. Lane ml owns q-row m0+ml;
    // acc[nt][r] = num[m0+ml][nt*16 + q4*4 + r] -> float4 stores.
    float* np = numW + ((size_t)idx * NSPLIT + s) * 4096 + (m0 + ml) * 64;
    #pragma unroll
    for (int nt = 0; nt < 4; ++nt)
        *(floatx4*)&np[nt * 16 + q4 * 4] = acc[nt];
    if (lane < 16) denW[((size_t)idx * NSPLIT + s) * 64 + m0 + lane] = acc[4][0];
}

// ---------------------------------------------------------------------------
// ONE cooperative kernel, 512 blocks x 256 threads, 4 phases with grid syncs.
// Replaces 4 separate launches (3 inter-kernel gaps + launch ramps).
// __launch_bounds__(256, 2): VGPR capped at 128 -> 2 blocks/CU guaranteed
// resident (LDS 34.8 KB/block, 69.6 KB/CU <= 160 KB) -> 512 blocks fit.
// Phase 1: qkv projection, 384 active blocks (24 nb x 16 mb).
// Phase 2: flash, units {bid, 1023-bid} (pairing balances kv-tile counts).
// Phase 3: combine 4 quarters -> y bf16, 256 active blocks.
// Phase 4: out = y @ Wo^T, 256 active blocks.
// ---------------------------------------------------------------------------
__global__ __launch_bounds__(256, 2) void fused_all(
    const void* __restrict__ hidR, const void* __restrict__ WqR,
    const void* __restrict__ WkR, const void* __restrict__ WvR,
    const void* __restrict__ WoR, void* __restrict__ outv,
    unsigned short* __restrict__ qb, unsigned short* __restrict__ kb,
    unsigned short* __restrict__ vt, unsigned short* __restrict__ yb,
    float* __restrict__ numW, float* __restrict__ denW) {
    cg::grid_group grid = cg::this_grid();
    __shared__ __align__(16) unsigned char smem[34816];   // union buffer
    __shared__ int cnt_sh;
    int bid = blockIdx.x, t = threadIdx.x;
    int fp32 = block_detect_fp32((const unsigned short*)WqR, &cnt_sh);

    // ================= Phase 1: QKV projection =================
    if (bid < 384) {
        unsigned short (*As)[136] = (unsigned short(*)[136])smem;
        unsigned short (*Bs)[136] = (unsigned short(*)[136])(smem + 17408);
        int nb = bid % 24, mb = bid / 24;
        const void* Braw; unsigned short* Cout; int ldc, col0, br0, isv;
        if (nb < 4)      { Braw = WqR; br0 = nb * 64;       Cout = qb; ldc = 256;  col0 = nb * 64;       isv = 0; }
        else if (nb < 8) { Braw = WkR; br0 = (nb - 4) * 64; Cout = kb; ldc = 256;  col0 = (nb - 4) * 64; isv = 0; }
        else             { Braw = WvR; br0 = (nb - 8) * 64; Cout = vt; ldc = 0;    col0 = (nb - 8) * 64; isv = 1; }

        floatx4 acc[4];
        gemm64_body(t, As, Bs, hidR, fp32, mb * 64, Braw, fp32, br0, 0, DMODEL, acc);

        int wave = (t >> 6) & 3, lane = t & 63;
        int ml = lane & 15, q4 = lane >> 4;
        int mq = (wave >> 1) * 32, nq = (wave & 1) * 32;
        if (!isv) {
            #pragma unroll
            for (int mi = 0; mi < 2; ++mi)
                #pragma unroll
                for (int ni = 0; ni < 2; ++ni) {
                    floatx4 a = acc[mi * 2 + ni];
                    int nloc = nq + ni * 16 + ml;
                    #pragma unroll
                    for (int r4 = 0; r4 < 4; ++r4) {
                        int row = mb * 64 + mq + mi * 16 + q4 * 4 + r4;
                        Cout[(size_t)row * ldc + col0 + nloc] = f2bf(a[r4]);
                    }
                }
        } else {
            #pragma unroll
            for (int mi = 0; mi < 2; ++mi)
                #pragma unroll
                for (int ni = 0; ni < 2; ++ni) {
                    floatx4 a = acc[mi * 2 + ni];
                    int nn = col0 + nq + ni * 16 + ml;                // vt row
                    int row0 = mb * 64 + mq + mi * 16 + q4 * 4;       // 4 consecutive l
                    ushort4 o;
                    o.x = f2bf(a[0]); o.y = f2bf(a[1]);
                    o.z = f2bf(a[2]); o.w = f2bf(a[3]);
                    *(ushort4*)&vt[(size_t)nn * 1024 + row0] = o;
                }
        }
    }
    grid.sync();

    // ================= Phase 2: flash attention partials =================
    {
        unsigned short (*qs)[40]  = (unsigned short(*)[40])smem;
        unsigned short (*ksm)[40] = (unsigned short(*)[40])(smem + 5120);
        unsigned short (*vT)[72]  = (unsigned short(*)[72])(smem + 10240);
        unsigned short (*P)[72]   = (unsigned short(*)[72])(smem + 21760);
        flash_unit(bid,        qs, ksm, vT, P, qb, kb, vt, numW, denW);
        flash_unit(1023 - bid, qs, ksm, vT, P, qb, kb, vt, numW, denW);
    }
    grid.sync();

    // ================= Phase 3: combine + normalize -> y =================
    if (bid < 256) {
        int idx = bid;
        int h = idx & 15, c = idx >> 4;
        int l0 = c * CHUNK;
        int row = t >> 2, col0 = (t & 3) * 16;
        const float* nb_ = numW + (size_t)idx * NSPLIT * 4096 + row * 64 + col0;
        const float* db_ = denW + (size_t)idx * NSPLIT * 64 + row;
        float den = db_[0] + db_[64] + db_[128] + db_[192] + 1e-12f;
        float dinv = 1.f / den;
        float sum[16];
        #pragma unroll
        for (int u = 0; u < 16; u += 4) {
            float4 a0 = *(const float4*)(nb_ + u);
            float4 a1 = *(const float4*)(nb_ + 4096 + u);
            float4 a2 = *(const float4*)(nb_ + 8192 + u);
            float4 a3 = *(const float4*)(nb_ + 12288 + u);
            sum[u + 0] = a0.x + a1.x + a2.x + a3.x;
            sum[u + 1] = a0.y + a1.y + a2.y + a3.y;
            sum[u + 2] = a0.z + a1.z + a2.z + a3.z;
            sum[u + 3] = a0.w + a1.w + a2.w + a3.w;
        }
        short8 o0, o1;
        #pragma unroll
        for (int u = 0; u < 8; ++u)  o0[u] = (short)f2bf(sum[u] * dinv);
        #pragma unroll
        for (int u = 0; u < 8; ++u)  o1[u] = (short)f2bf(sum[u + 8] * dinv);
        unsigned short* yp = yb + (size_t)(l0 + row) * 1024 + h * 64 + col0;
        *(short8*)yp       = o0;
        *(short8*)(yp + 8) = o1;
    }
    grid.sync();

    // ================= Phase 4: output projection =================
    if (bid < 256) {
        unsigned short (*As)[136] = (unsigned short(*)[136])smem;
        unsigned short (*Bs)[136] = (unsigned short(*)[136])(smem + 17408);
        int nb = bid & 15, mb = bid >> 4;

        floatx4 acc[4];
        gemm64_body(t, As, Bs, yb, 0, mb * 64, WoR, fp32, nb * 64, 0, DMODEL, acc);

        int wave = (t >> 6) & 3, lane = t & 63;
        int ml = lane & 15, q4 = lane >> 4;
        int mq = (wave >> 1) * 32, nq = (wave & 1) * 32;
        #pragma unroll
        for (int mi = 0; mi < 2; ++mi)
            #pragma unroll
            for (int ni = 0; ni < 2; ++ni) {
                floatx4 a = acc[mi * 2 + ni];
                int nn = nb * 64 + nq + ni * 16 + ml;
                #pragma unroll
                for (int r4 = 0; r4 < 4; ++r4) {
                    int row = mb * 64 + mq + mi * 16 + q4 * 4 + r4;
                    size_t oidx = (size_t)row * 1024 + nn;
                    if (fp32) ((float*)outv)[oidx] = a[r4];
                    else      ((unsigned short*)outv)[oidx] = f2bf(a[r4]);
                }
            }
    }
}

// ---------------------------------------------------------------------------
extern "C" void kernel_launch(void* const* d_in, const int* in_sizes, int n_in,
                              void* d_out, int out_size, void* d_ws, size_t ws_size,
                              hipStream_t stream) {
    unsigned short* us = (unsigned short*)d_ws;
    unsigned short* qbB = us + U_QB;
    unsigned short* kbB = us + U_KB;
    unsigned short* vtB = us + U_VT;
    unsigned short* ybB = us + U_YB;
    float* fws  = (float*)(us + U_END);       // byte offset 5242880, 256B-aligned
    float* numW = fws;                        // 4194304 floats
    float* denW = fws + 4194304;              // 65536 floats
    size_t need = (size_t)U_END * 2ull + (size_t)(4194304 + 65536) * 4ull;
    if (ws_size < need) return;

    void* hidR = d_in[0]; void* WqR = d_in[1]; void* WkR = d_in[2];
    void* WvR = d_in[3];  void* WoR = d_in[4]; void* outv = d_out;
    void* args[] = { &hidR, &WqR, &WkR, &WvR, &WoR, &outv,
                     &qbB, &kbB, &vtB, &ybB, &numW, &denW };
    hipLaunchCooperativeKernel((const void*)fused_all, dim3(512), dim3(256),
                               args, 0, stream);
}

// Round 7
// 135.381 us; speedup vs baseline: 2.4578x; 2.4578x over previous
//
#include <hip/hip_runtime.h>

// Problem constants
#define LSEQ 1024
#define DMODEL 1024
#define NHEADS 16
#define FDIM 16
#define HDIM 64
#define CHUNK 64
#define NCHUNK 16
#define NSPLIT 4

typedef __attribute__((ext_vector_type(8))) short short8;   // 8 bf16 (4 VGPRs)
typedef __attribute__((ext_vector_type(4))) float floatx4;  // MFMA acc

// Hardware RNE f32->bf16 (v_cvt_pk_bf16_f32).
__device__ __forceinline__ unsigned short f2bf(float f) {
    return __builtin_bit_cast(unsigned short, (__bf16)f);
}

// Per-block dtype detector: samples 1024 ushorts of Wq. bf16 data -> exponents
// cluster tightly (bad ~0%); fp32-as-ushort -> half the samples are uniform
// mantissa bits (bad ~30%+). Returns 1 if inputs are fp32.
__device__ __forceinline__ int block_detect_fp32(const unsigned short* wq) {
    __shared__ int cnt;
    if (threadIdx.x == 0) cnt = 0;
    __syncthreads();
    int bad = 0;
    for (int i = threadIdx.x; i < 1024; i += blockDim.x) {
        int e = (wq[i] >> 7) & 0xFF;
        if (e >= 143 || (e > 0 && e <= 80)) bad++;
    }
    if (bad) atomicAdd(&cnt, bad);
    __syncthreads();
    return cnt > 128;
}

// Workspace layout (ushort indices):
//   qbB @0        (262144)   bf16 q   [1024][256]   row-major [l][h*16+d]
//   kbB @262144   (262144)   bf16 k   [1024][256]   row-major
//   vtB @524288   (1048576)  bf16 v^T [1024][1024]  TRANSPOSED: [h*64+d][l]
//   ybB @1572864  (1048576)  bf16 y   [1024][1024]
//   fp32 partials @ byte offset 5242880:
//   numW  [256][4][64][64] fp32   (4194304 floats)   [c*16+h][s][qrow][d]
//   denW  [256][4][64]     fp32   (65536 floats)
#define U_QB   0
#define U_KB   262144
#define U_VT   524288
#define U_YB   1572864
#define U_END  2621440

#define MFMA(a, b, c) __builtin_amdgcn_mfma_f32_16x16x32_bf16((a), (b), (c), 0, 0, 0)

// ---------------------------------------------------------------------------
// Pipelined 64x64 GEMM tile body over K = [kbeg, kend), BK = 128, with
// DEPTH-2 register ping-pong prefetch: two stage-sets (A/B); each set is
// written to LDS and immediately re-used to issue the load 2 iterations
// ahead, so every global load gets ~2 full iterations (~2x(2 barriers +
// 16 MFMA + LDS ops)) of latency cover instead of just the MFMA window.
// Requires (kend - kbeg) % 256 == 0 (we use 512). Same registers, same
// barrier count, same LDS as the 1-deep version — only the issue point
// moves earlier. fp32 inputs staged with float4 loads + HW cvt.
// acc order: 00,01,10,11 (mi*2+ni). t = 0..255.
// ---------------------------------------------------------------------------
__device__ __forceinline__ void gemm64_body(
    int t, unsigned short (*As)[136], unsigned short (*Bs)[136],
    const void* Araw, int a_fp32, int arow0,
    const void* Braw, int b_fp32, int brow0,
    int kbeg, int kend, floatx4 acc[4]) {
    int r = t >> 2, c0 = (t & 3) * 32;
    int wave = (t >> 6) & 3, lane = t & 63;
    int ml = lane & 15, q4 = lane >> 4;
    int mq = (wave >> 1) * 32, nq = (wave & 1) * 32;
    #pragma unroll
    for (int i = 0; i < 4; ++i) acc[i] = (floatx4){0.f, 0.f, 0.f, 0.f};

    short8 avA[4], bvA[4], avB[4], bvB[4];
    auto cvt8 = [](float4 f0, float4 f1) {
        short8 x;
        x[0] = (short)f2bf(f0.x); x[1] = (short)f2bf(f0.y);
        x[2] = (short)f2bf(f0.z); x[3] = (short)f2bf(f0.w);
        x[4] = (short)f2bf(f1.x); x[5] = (short)f2bf(f1.y);
        x[6] = (short)f2bf(f1.z); x[7] = (short)f2bf(f1.w);
        return x;
    };
    auto stage = [&](int k0, short8* a, short8* b) {
        if (!a_fp32) {
            const unsigned short* Ap = (const unsigned short*)Araw + (size_t)(arow0 + r) * DMODEL + k0 + c0;
            #pragma unroll
            for (int j = 0; j < 4; ++j) a[j] = *(const short8*)(Ap + j * 8);
        } else {
            const float* Ap = (const float*)Araw + (size_t)(arow0 + r) * DMODEL + k0 + c0;
            #pragma unroll
            for (int j = 0; j < 4; ++j)
                a[j] = cvt8(*(const float4*)(Ap + j * 8), *(const float4*)(Ap + j * 8 + 4));
        }
        if (!b_fp32) {
            const unsigned short* Bp = (const unsigned short*)Braw + (size_t)(brow0 + r) * DMODEL + k0 + c0;
            #pragma unroll
            for (int j = 0; j < 4; ++j) b[j] = *(const short8*)(Bp + j * 8);
        } else {
            const float* Bp = (const float*)Braw + (size_t)(brow0 + r) * DMODEL + k0 + c0;
            #pragma unroll
            for (int j = 0; j < 4; ++j)
                b[j] = cvt8(*(const float4*)(Bp + j * 8), *(const float4*)(Bp + j * 8 + 4));
        }
    };
    auto lds_write = [&](short8* a, short8* b) {
        #pragma unroll
        for (int j = 0; j < 4; ++j) {
            *(short8*)&As[r][c0 + j * 8] = a[j];
            *(short8*)&Bs[r][c0 + j * 8] = b[j];
        }
    };
    auto mfma16 = [&]() {
        #pragma unroll
        for (int kk = 0; kk < 4; ++kk) {
            short8 a0 = *(const short8*)&As[mq + ml][kk * 32 + q4 * 8];
            short8 a1 = *(const short8*)&As[mq + 16 + ml][kk * 32 + q4 * 8];
            short8 b0 = *(const short8*)&Bs[nq + ml][kk * 32 + q4 * 8];
            short8 b1 = *(const short8*)&Bs[nq + 16 + ml][kk * 32 + q4 * 8];
            acc[0] = MFMA(a0, b0, acc[0]); acc[1] = MFMA(a0, b1, acc[1]);
            acc[2] = MFMA(a1, b0, acc[2]); acc[3] = MFMA(a1, b1, acc[3]);
        }
    };

    stage(kbeg, avA, bvA);
    stage(kbeg + 128, avB, bvB);
    for (int k0 = kbeg; k0 < kend; k0 += 256) {
        // ---- phase A (tile k0)
        __syncthreads();                 // previous phase's LDS reads done
        lds_write(avA, bvA);
        __syncthreads();                 // LDS ready
        if (k0 + 256 < kend) stage(k0 + 256, avA, bvA);   // 2 iters ahead
        mfma16();
        // ---- phase B (tile k0 + 128)
        __syncthreads();
        lds_write(avB, bvB);
        __syncthreads();
        if (k0 + 384 < kend) stage(k0 + 384, avB, bvB);
        mfma16();
    }
}

// ---------------------------------------------------------------------------
// Intra-block split-K reduction: half 1 parks its fp32 acc in the retired
// As0 buffer (layout [col][row] padded to 68 rows: col stride 272 B is
// 16B-aligned and shifts 4 banks/col), half 0 adds it into its own acc.
// 64x64 fp32 = 16 KB <= As0's 17.4 KB. Returns true for threads that
// should run the epilogue (half 0).
// ---------------------------------------------------------------------------
__device__ __forceinline__ bool splitk_reduce(
    int t, int hf, float* red, floatx4 acc[4]) {
    int wave = (t >> 6) & 3, lane = t & 63;
    int ml = lane & 15, q4 = lane >> 4;
    int mq = (wave >> 1) * 32, nq = (wave & 1) * 32;
    __syncthreads();   // all LDS reads of the K-loop done
    if (hf) {
        #pragma unroll
        for (int mi = 0; mi < 2; ++mi)
            #pragma unroll
            for (int ni = 0; ni < 2; ++ni)
                *(floatx4*)&red[(nq + ni * 16 + ml) * 68 + mq + mi * 16 + q4 * 4] = acc[mi * 2 + ni];
    }
    __syncthreads();
    if (hf) return false;
    #pragma unroll
    for (int mi = 0; mi < 2; ++mi)
        #pragma unroll
        for (int ni = 0; ni < 2; ++ni) {
            floatx4 o = *(const floatx4*)&red[(nq + ni * 16 + ml) * 68 + mq + mi * 16 + q4 * 4];
            acc[mi * 2 + ni] = acc[mi * 2 + ni] + o;
        }
    return true;
}

// ---------------------------------------------------------------------------
// Kernel 1: QKV projection, 512-thread intra-block split-K.
// grid (24, 16): nb 0..3 q, 4..7 k, 8..23 v. Waves 0-3: K=[0,512),
// waves 4-7: K=[512,1024) in a second LDS pair; LDS combine; half 0 writes.
// v is written TRANSPOSED (vt[h*64+d][l]) so flash can stage V^T with
// coalesced loads + vector LDS writes.
// ---------------------------------------------------------------------------
__global__ __launch_bounds__(512) void qkv_gemm(
    const void* __restrict__ hidR, const void* __restrict__ WqR,
    const void* __restrict__ WkR, const void* __restrict__ WvR,
    unsigned short* __restrict__ qb, unsigned short* __restrict__ kb,
    unsigned short* __restrict__ vt) {
    int fp32 = block_detect_fp32((const unsigned short*)WqR);
    __shared__ __align__(16) unsigned short As0[64][136], Bs0[64][136];
    __shared__ __align__(16) unsigned short As1[64][136], Bs1[64][136];
    int t = threadIdx.x & 255, hf = threadIdx.x >> 8;
    int nb = blockIdx.x, mb = blockIdx.y;
    const void* Braw; unsigned short* Cout; int ldc, col0, br0, isv;
    if (nb < 4)      { Braw = WqR; br0 = nb * 64;       Cout = qb; ldc = 256;  col0 = nb * 64;       isv = 0; }
    else if (nb < 8) { Braw = WkR; br0 = (nb - 4) * 64; Cout = kb; ldc = 256;  col0 = (nb - 4) * 64; isv = 0; }
    else             { Braw = WvR; br0 = (nb - 8) * 64; Cout = vt; ldc = 0;    col0 = (nb - 8) * 64; isv = 1; }

    floatx4 acc[4];
    gemm64_body(t, hf ? As1 : As0, hf ? Bs1 : Bs0,
                hidR, fp32, mb * 64, Braw, fp32, br0,
                hf * 512, hf * 512 + 512, acc);
    if (!splitk_reduce(t, hf, (float*)As0, acc)) return;

    int wave = (t >> 6) & 3, lane = t & 63;
    int ml = lane & 15, q4 = lane >> 4;
    int mq = (wave >> 1) * 32, nq = (wave & 1) * 32;
    if (!isv) {
        #pragma unroll
        for (int mi = 0; mi < 2; ++mi)
            #pragma unroll
            for (int ni = 0; ni < 2; ++ni) {
                floatx4 a = acc[mi * 2 + ni];
                int nloc = nq + ni * 16 + ml;
                #pragma unroll
                for (int r4 = 0; r4 < 4; ++r4) {
                    int row = mb * 64 + mq + mi * 16 + q4 * 4 + r4;
                    Cout[(size_t)row * ldc + col0 + nloc] = f2bf(a[r4]);
                }
            }
    } else {
        #pragma unroll
        for (int mi = 0; mi < 2; ++mi)
            #pragma unroll
            for (int ni = 0; ni < 2; ++ni) {
                floatx4 a = acc[mi * 2 + ni];
                int n = col0 + nq + ni * 16 + ml;                 // vt row
                int row0 = mb * 64 + mq + mi * 16 + q4 * 4;       // 4 consecutive l
                ushort4 o;
                o.x = f2bf(a[0]); o.y = f2bf(a[1]);
                o.z = f2bf(a[2]); o.w = f2bf(a[3]);
                *(ushort4*)&vt[(size_t)n * 1024 + row0] = o;
            }
    }
}

// ---------------------------------------------------------------------------
// Kernel 2: flash-style quadratic polynomial attention, kv-range split 4-way,
// fence-free. S(l,t) = 1 + (q.k)/4 + (q.k)^2/32, causal; partials only.
// Block (h, c, s): Q rows [64c, +64); with n = c+1 tiles, split s handles
// j in [n*s/4, n*(s+1)/4) (exact partition; diagonal always in s=3).
// QK^T computed SWAPPED (MFMA(K, Q)): lane owns q-row m0+ml with 4
// consecutive t-values per nt -> P store is 4x ds_write_b64.
// PV computed TRANSPOSED (O^T = MFMA(vT_frag, P_frag)): lane ml owns one
// q-row with 16 consecutive d -> float4 partial stores, shuffle-free den.
// ---------------------------------------------------------------------------
__global__ __launch_bounds__(256) void flash_partial(
    const unsigned short* __restrict__ qb, const unsigned short* __restrict__ kb,
    const unsigned short* __restrict__ vt,
    float* __restrict__ numW, float* __restrict__ denW) {
    int idx = blockIdx.x & 255;          // (h, c)
    int s = blockIdx.x >> 8;             // kv-range quarter, 0..3
    int h = idx & 15, c = idx >> 4;
    int n = c + 1;
    int j0 = (n * s) >> 2;
    int j1 = ((n * (s + 1)) >> 2) - 1;   // inclusive; empty when j0 > j1
    int l0 = c * CHUNK;
    __shared__ __align__(16) unsigned short qs[64][40];
    __shared__ __align__(16) unsigned short ksm[64][40];
    __shared__ __align__(16) unsigned short vT[80][72];   // rows 0..63 v^T, 64 ones
    __shared__ __align__(16) unsigned short P[64][72];
    int t = threadIdx.x, lane = t & 63, wave = t >> 6;
    int ml = lane & 15, q4 = lane >> 4;
    int m0 = wave * 16;
    int sm = t >> 2, si4 = (t & 3) * 4, sc16 = (t & 3) * 16;

    // ---- one-time staging: q rows (zero-padded K=32), vT pad rows
    {
        *(ushort4*)&qs[sm][si4] = *(const ushort4*)&qb[(size_t)(l0 + sm) * 256 + h * 16 + si4];
        ushort4 z = {0, 0, 0, 0};
        *(ushort4*)&qs[sm][16 + si4]  = z;
        *(ushort4*)&ksm[sm][16 + si4] = z;   // k pad, persists across tiles
    }
    if (t < 64) {
        vT[64][t] = 0x3F80;   // 1.0 bf16 (denominator row)
        #pragma unroll
        for (int i = 65; i < 80; ++i) vT[i][t] = 0;
    }

    auto load_kv = [&](int j, ushort4& kr, short8& v0, short8& v1) {
        kr = *(const ushort4*)&kb[(size_t)(j * 64 + sm) * 256 + h * 16 + si4];
        const unsigned short* vp = vt + (size_t)(h * 64 + sm) * 1024 + j * 64 + sc16;
        v0 = *(const short8*)vp;
        v1 = *(const short8*)(vp + 8);
    };

    floatx4 acc[5];
    #pragma unroll
    for (int i = 0; i < 5; ++i) acc[i] = (floatx4){0.f, 0.f, 0.f, 0.f};

    ushort4 kr, kr2; short8 va, vb2, va2, vb22;
    if (j0 <= j1) {
        load_kv(j0, kr, va, vb2);
        for (int j = j0; j <= j1; ++j) {
            // ---- write prefetched k_j / v_j^T to LDS (all vectorized)
            *(ushort4*)&ksm[sm][si4] = kr;
            *(short8*)&vT[sm][sc16]     = va;
            *(short8*)&vT[sm][sc16 + 8] = vb2;
            __syncthreads();   // staging visible (also covers qs/pads on first iter)
            if (j < j1) load_kv(j + 1, kr2, va2, vb22);   // overlap with MFMAs

            // ---- scores, swapped: MFMA(K,Q) -> lane(q4,ml) reg r holds
            // S[q=m0+ml][t=nt*16+q4*4+r]; P row store is one ushort4 per nt.
            short8 aq = *(const short8*)&qs[m0 + ml][q4 * 8];
            bool diag = (j == c);
            int qloc = m0 + ml;
            #pragma unroll
            for (int nt = 0; nt < 4; ++nt) {
                short8 bk = *(const short8*)&ksm[nt * 16 + ml][q4 * 8];
                floatx4 s4 = {0.f, 0.f, 0.f, 0.f};
                s4 = MFMA(bk, aq, s4);
                ushort4 pw;
                #pragma unroll
                for (int r = 0; r < 4; ++r) {
                    int tloc = nt * 16 + q4 * 4 + r;
                    float sc = s4[r];
                    float p = 1.f + 0.25f * sc + 0.03125f * sc * sc;
                    if (diag && tloc > qloc) p = 0.f;
                    ((unsigned short*)&pw)[r] = f2bf(p);
                }
                *(ushort4*)&P[qloc][nt * 16 + q4 * 4] = pw;
            }
            // P rows are wave-private (rows m0..m0+15 written and read by this
            // wave only): no barrier needed before PV.

            // ---- PV transposed: acc[nt] = O^T block (A = vT rows, B = P rows)
            #pragma unroll
            for (int k0 = 0; k0 < 64; k0 += 32) {
                short8 ap = *(const short8*)&P[m0 + ml][k0 + q4 * 8];
                #pragma unroll
                for (int nt = 0; nt < 5; ++nt) {
                    short8 av = *(const short8*)&vT[nt * 16 + ml][k0 + q4 * 8];
                    acc[nt] = MFMA(av, ap, acc[nt]);
                }
            }
            __syncthreads();   // protect ksm/vT from next tile's staging
            kr = kr2; va = va2; vb2 = vb22;
        }
    }

    // ---- write fp32 partials. Lane ml owns q-row m0+ml;
    // acc[nt][r] = num[m0+ml][nt*16 + q4*4 + r] -> float4 stores.
    float* np = numW + ((size_t)idx * NSPLIT + s) * 4096 + (m0 + ml) * 64;
    #pragma unroll
    for (int nt = 0; nt < 4; ++nt)
        *(floatx4*)&np[nt * 16 + q4 * 4] = acc[nt];
    // den[m0+ml] sits in acc[4][0] of lanes 0..15 (ones-row is vT row 64).
    if (lane < 16) denW[((size_t)idx * NSPLIT + s) * 64 + m0 + lane] = acc[4][0];
}

// ---------------------------------------------------------------------------
// Kernel 2b: combine the four kv-quarters and normalize:
// y = (n0+n1+n2+n3)/(d0+d1+d2+d3+eps) -> bf16. One pass over 17 MB, ~3 us.
// Grid 256 (one block per (h,c)), 256 threads; thread t -> row t>>2,
// cols (t&3)*16 .. +16.
// ---------------------------------------------------------------------------
__global__ __launch_bounds__(256) void attn_combine(
    const float* __restrict__ numW, const float* __restrict__ denW,
    unsigned short* __restrict__ ybB) {
    int idx = blockIdx.x;
    int h = idx & 15, c = idx >> 4;
    int l0 = c * CHUNK;
    int t = threadIdx.x;
    int row = t >> 2, col0 = (t & 3) * 16;
    const float* nb_ = numW + (size_t)idx * NSPLIT * 4096 + row * 64 + col0;
    const float* db_ = denW + (size_t)idx * NSPLIT * 64 + row;
    float den = db_[0] + db_[64] + db_[128] + db_[192] + 1e-12f;
    float dinv = 1.f / den;
    float sum[16];
    #pragma unroll
    for (int u = 0; u < 16; u += 4) {
        float4 a0 = *(const float4*)(nb_ + u);
        float4 a1 = *(const float4*)(nb_ + 4096 + u);
        float4 a2 = *(const float4*)(nb_ + 8192 + u);
        float4 a3 = *(const float4*)(nb_ + 12288 + u);
        sum[u + 0] = a0.x + a1.x + a2.x + a3.x;
        sum[u + 1] = a0.y + a1.y + a2.y + a3.y;
        sum[u + 2] = a0.z + a1.z + a2.z + a3.z;
        sum[u + 3] = a0.w + a1.w + a2.w + a3.w;
    }
    short8 o0, o1;
    #pragma unroll
    for (int u = 0; u < 8; ++u)  o0[u] = (short)f2bf(sum[u] * dinv);
    #pragma unroll
    for (int u = 0; u < 8; ++u)  o1[u] = (short)f2bf(sum[u + 8] * dinv);
    unsigned short* yp = ybB + (size_t)(l0 + row) * 1024 + h * 64 + col0;
    *(short8*)yp       = o0;
    *(short8*)(yp + 8) = o1;
}

// ---------------------------------------------------------------------------
// Kernel 3: output projection, 512-thread intra-block split-K.
// out = y @ Wo^T (1024^3), bf16 A staging. Output dtype per detector.
// ---------------------------------------------------------------------------
__global__ __launch_bounds__(512) void out_gemm(
    const unsigned short* __restrict__ A, const void* __restrict__ WoR,
    void* __restrict__ outv, const unsigned short* __restrict__ wqraw) {
    int fp32 = block_detect_fp32(wqraw);
    __shared__ __align__(16) unsigned short As0[64][136], Bs0[64][136];
    __shared__ __align__(16) unsigned short As1[64][136], Bs1[64][136];
    int t = threadIdx.x & 255, hf = threadIdx.x >> 8;
    int nb = blockIdx.x, mb = blockIdx.y;

    floatx4 acc[4];
    gemm64_body(t, hf ? As1 : As0, hf ? Bs1 : Bs0,
                A, 0, mb * 64, WoR, fp32, nb * 64,
                hf * 512, hf * 512 + 512, acc);
    if (!splitk_reduce(t, hf, (float*)As0, acc)) return;

    int wave = (t >> 6) & 3, lane = t & 63;
    int ml = lane & 15, q4 = lane >> 4;
    int mq = (wave >> 1) * 32, nq = (wave & 1) * 32;
    #pragma unroll
    for (int mi = 0; mi < 2; ++mi)
        #pragma unroll
        for (int ni = 0; ni < 2; ++ni) {
            floatx4 a = acc[mi * 2 + ni];
            int nn = nb * 64 + nq + ni * 16 + ml;
            #pragma unroll
            for (int r4 = 0; r4 < 4; ++r4) {
                int row = mb * 64 + mq + mi * 16 + q4 * 4 + r4;
                size_t oidx = (size_t)row * 1024 + nn;
                if (fp32) ((float*)outv)[oidx] = a[r4];
                else      ((unsigned short*)outv)[oidx] = f2bf(a[r4]);
            }
        }
}

// ---------------------------------------------------------------------------
extern "C" void kernel_launch(void* const* d_in, const int* in_sizes, int n_in,
                              void* d_out, int out_size, void* d_ws, size_t ws_size,
                              hipStream_t stream) {
    unsigned short* us = (unsigned short*)d_ws;
    unsigned short* qbB = us + U_QB;
    unsigned short* kbB = us + U_KB;
    unsigned short* vtB = us + U_VT;
    unsigned short* ybB = us + U_YB;
    float* fws  = (float*)(us + U_END);       // byte offset 5242880, 256B-aligned
    float* numW = fws;                        // 4194304 floats
    float* denW = fws + 4194304;              // 65536 floats
    size_t need = (size_t)U_END * 2ull + (size_t)(4194304 + 65536) * 4ull;
    if (ws_size < need) return;

    qkv_gemm<<<dim3(24, 16), 512, 0, stream>>>(d_in[0], d_in[1], d_in[2], d_in[3], qbB, kbB, vtB);
    flash_partial<<<dim3(1024), 256, 0, stream>>>(qbB, kbB, vtB, numW, denW);
    attn_combine<<<dim3(256), 256, 0, stream>>>(numW, denW, ybB);
    out_gemm<<<dim3(16, 16), 512, 0, stream>>>(ybB, d_in[4], d_out, (const unsigned short*)d_in[1]);
}